// Round 16
// baseline (62.383 us; speedup 1.0000x reference)
//
#include <hip/hip_runtime.h>

#define BN_EPS 1e-5f
#define LOG2E 1.44269504088896340736f

typedef const float* fp;
typedef float f32x4 __attribute__((ext_vector_type(4)));
typedef _Float16 f16x2 __attribute__((ext_vector_type(2)));
typedef _Float16 f16x4 __attribute__((ext_vector_type(4)));
typedef _Float16 f16x8 __attribute__((ext_vector_type(8)));
typedef unsigned u32x4 __attribute__((ext_vector_type(4)));

__device__ __forceinline__ float frcp(float x) { return __builtin_amdgcn_rcpf(x); }
__device__ __forceinline__ float fexp2(float x) { return __builtin_amdgcn_exp2f(x); }
// reference-formula transcendentals (used in k_out, unchanged)
__device__ __forceinline__ float sigm(float x) { return frcp(1.0f + __expf(-x)); }

__device__ __forceinline__ f32x4 ld4(const float* p) { return *(const f32x4*)p; }
__device__ __forceinline__ float dot4(f32x4 a, f32x4 b) {
    return a[0] * b[0] + a[1] * b[1] + a[2] * b[2] + a[3] * b[3];
}

#define MFMA32(A, B, C) __builtin_amdgcn_mfma_f32_16x16x32_f16((A), (B), (C), 0, 0, 0)

// async global->LDS, 16B per lane; dest = uniform base + lane*16 (HW rule).
#define GLDS16(gp, lp) __builtin_amdgcn_global_load_lds( \
    (const __attribute__((address_space(1))) void*)(gp), \
    (__attribute__((address_space(3))) void*)(lp), 16, 0, 0)

// pack f32x4 -> f16x4 via v_cvt_pkrtz (2 inst).
__device__ __forceinline__ f16x4 pk_f16(f32x4 v) {
    f16x2 lo = __builtin_bit_cast(f16x2, __builtin_amdgcn_cvt_pkrtz(v[0], v[1]));
    f16x2 hi = __builtin_bit_cast(f16x2, __builtin_amdgcn_cvt_pkrtz(v[2], v[3]));
    return __builtin_shufflevector(lo, hi, 0, 1, 2, 3);
}

// ---------------------------------------------------------------------------
// K0: zero stats1[96] + stats2[32].
// ---------------------------------------------------------------------------
__global__ void k_zero(float* __restrict__ stats) { stats[threadIdx.x] = 0.f; }

// ---------------------------------------------------------------------------
// K2: MFMA GRU, 16 samples/wave, 4-step unrolled loop. SINGLE CHANGE vs R15:
// staging ring 8 -> 12 slots (prefetch distance 12 steps, issue->consume gap
// ~2.5 iterations, fence vmcnt(8)) — decisive test of the gather-latency
// theory for the unattributed ~2/3 idle cycles. Slot = t mod 12; base steps
// by 4 so each iteration's 4 slots are contiguous (so in {0,4,8}); restage
// targets the just-consumed slots (WAR clear via lgkmcnt(0)). LDS 68KB/block
// keeps 2 blocks/CU (136 <= 160KB). Math identical to R15 (absmax must stay
// 0.00390625). Requires T <= 52 (ids padded/clamped to 64).
// ---------------------------------------------------------------------------
__device__ __forceinline__ void gru_step_h(
    f32x4 xr, f32x4 xz, f32x4 xn,
    const f16x8& Ahr, const f16x8& Ahz, const f16x8& Ahn, const f32x4& bhn4,
    f32x4& h, f32x4& hsum, f16x4& hh)
{
    f16x8 Bh2 = __builtin_shufflevector(hh, hh, 0, 1, 2, 3, 0, 1, 2, 3);
    f32x4 sR = MFMA32(Ahr, Bh2, xr);    // = -1.4427 * (r preact)
    f32x4 sZ = MFMA32(Ahz, Bh2, xz);    // = -1.4427 * (z preact)
    f32x4 hn = MFMA32(Ahn, Bh2, bhn4);  // =  2.8854 * (hn part)
    f32x4 r, z, nv;
#pragma unroll
    for (int q = 0; q < 4; ++q) {
        float a  = fexp2(sR[q]);
        float bb = fexp2(sZ[q]);
        float pa = 1.0f + a, pb = 1.0f + bb;
        float iD = frcp(pa * pb);
        r[q] = pb * iD;
        z[q] = pa * iD;
    }
    f32x4 pre = r * hn + xn;            // = 2.8854 * (n preact)
#pragma unroll
    for (int q = 0; q < 4; ++q)
        nv[q] = 1.0f - 2.0f * frcp(1.0f + fexp2(pre[q]));
    h = z * (h - nv) + nv;
    hsum += h;
    hh = pk_f16(h);
}

__global__ __launch_bounds__(256, 2) void k_gru(
    const int* __restrict__ user_id, const int* __restrict__ hist_item,
    const int* __restrict__ hist_cat, const int* __restrict__ tgt_item,
    const int* __restrict__ tgt_cat,
    fp user_table, fp item_table, fp cat_table,
    fp Whh, fp bhh, fp Wih, fp bih,
    fp mha_Win, fp mha_bin, fp mha_Wout, fp mha_bout,
    float* __restrict__ all_enc, float* __restrict__ stats1, int B, int T)
{
    __shared__ float    s_stage[4][12][256];  // 48KB [wave][slot][lane*4]
    __shared__ unsigned s_ids[4][16 * 68];    // 17.4KB packed (cd<<16)|id
    __shared__ float    lds_part[4][96];

    const int tid  = threadIdx.x;
    const int lane = tid & 63;
    const int wid  = tid >> 6;
    const int s    = lane & 15;
    const int hi   = lane >> 4;

    long b = (long)blockIdx.x * 64 + wid * 16 + s;
    const bool act = (b < B);
    if (!act) b = B - 1;

    // epilogue indices: materialize before the barrier (VMEM retires there)
    const int ti  = tgt_item[b];
    const int tc  = tgt_cat[b];
    const int uid = user_id[b];
    asm volatile("" :: "v"(ti), "v"(tc), "v"(uid));

    const int T1 = T - 1;

    // one-time packed id preload into LDS, padded with clamped ids to idx 63
    {
        const int* ip = hist_item + b * T;
        const int* cp = hist_cat  + b * T;
        unsigned* d = &s_ids[wid][s * 68];
        for (int k = hi; k < 64; k += 4) {
            int src = (k <= T1) ? k : T1;
            d[k] = (unsigned)ip[src] | ((unsigned)cp[src] << 16);
        }
    }

    // ---- weight fragments + constant gate biases (one-time) ----
    // exp-scales folded: r,z sets * -log2(e); n set * +2*log2(e).
    const float sRZ = -LOG2E, sN = 2.0f * LOG2E;
    f32x4 wirf = ld4(&Wih[(0  + s) * 16 + 4 * hi]) * sRZ;
    f32x4 wizf = ld4(&Wih[(16 + s) * 16 + 4 * hi]) * sRZ;
    f32x4 winf = ld4(&Wih[(32 + s) * 16 + 4 * hi]) * sN;
    f32x4 whrf = ld4(&Whh[(0  + s) * 16 + 4 * hi]) * sRZ;
    f32x4 whzf = ld4(&Whh[(16 + s) * 16 + 4 * hi]) * sRZ;
    f32x4 whnf = ld4(&Whh[(32 + s) * 16 + 4 * hi]) * sN;
    f16x4 wir_h = __builtin_convertvector(wirf, f16x4);
    f16x4 wiz_h = __builtin_convertvector(wizf, f16x4);
    f16x4 win_h = __builtin_convertvector(winf, f16x4);
    f16x4 whr_h = __builtin_convertvector(whrf, f16x4);
    f16x4 whz_h = __builtin_convertvector(whzf, f16x4);
    f16x4 whn_h = __builtin_convertvector(whnf, f16x4);
    f16x4 wir_l = __builtin_convertvector(wirf - __builtin_convertvector(wir_h, f32x4), f16x4);
    f16x4 wiz_l = __builtin_convertvector(wizf - __builtin_convertvector(wiz_h, f32x4), f16x4);
    f16x4 win_l = __builtin_convertvector(winf - __builtin_convertvector(win_h, f32x4), f16x4);
    f16x4 whr_l = __builtin_convertvector(whrf - __builtin_convertvector(whr_h, f32x4), f16x4);
    f16x4 whz_l = __builtin_convertvector(whzf - __builtin_convertvector(whz_h, f32x4), f16x4);
    f16x4 whn_l = __builtin_convertvector(whnf - __builtin_convertvector(whn_h, f32x4), f16x4);
    f16x8 Air = __builtin_shufflevector(wir_h, wir_l, 0, 1, 2, 3, 4, 5, 6, 7);
    f16x8 Aiz = __builtin_shufflevector(wiz_h, wiz_l, 0, 1, 2, 3, 4, 5, 6, 7);
    f16x8 Ain = __builtin_shufflevector(win_h, win_l, 0, 1, 2, 3, 4, 5, 6, 7);
    f16x8 Ahr = __builtin_shufflevector(whr_h, whr_l, 0, 1, 2, 3, 4, 5, 6, 7);
    f16x8 Ahz = __builtin_shufflevector(whz_h, whz_l, 0, 1, 2, 3, 4, 5, 6, 7);
    f16x8 Ahn = __builtin_shufflevector(whn_h, whn_l, 0, 1, 2, 3, 4, 5, 6, 7);
    const f32x4 br4  = (ld4(&bih[4 * hi])      + ld4(&bhh[4 * hi]))      * sRZ;
    const f32x4 bz4  = (ld4(&bih[16 + 4 * hi]) + ld4(&bhh[16 + 4 * hi])) * sRZ;
    const f32x4 bxn4 = ld4(&bih[32 + 4 * hi]) * sN;
    const f32x4 bhn4 = ld4(&bhh[32 + 4 * hi]) * sN;

    f32x4 h = {0.f, 0.f, 0.f, 0.f}, hsum = {0.f, 0.f, 0.f, 0.f};
    f16x4 hh = {};

    __syncthreads();   // ids ready; all prologue VMEM drained here

    const unsigned* idsrow = &s_ids[wid][s * 68];
    float* stg = &s_stage[wid][0][0];
    const int l4 = lane * 4;

    // per-lane gather parameters
    const char*   gb   = (hi < 3) ? (const char*)item_table + hi * 16
                                  : (const char*)cat_table;
    const unsigned gsh  = (hi < 3) ? 0u : 16u;
    const unsigned gmul = (hi < 3) ? 48u : 16u;
#define GADDR(pk) (gb + (size_t)(((pk) >> gsh) & 0xffffu) * gmul)

    // prologue: stage slots 0..11 (steps 0..11, clamped); prefetch ids[12..15]
#pragma unroll
    for (int d = 0; d < 3; ++d) {
        u32x4 iq = *(const u32x4*)&idsrow[d * 4];
        GLDS16(GADDR(iq[0]), stg + (d * 4 + 0) * 256);
        GLDS16(GADDR(iq[1]), stg + (d * 4 + 1) * 256);
        GLDS16(GADDR(iq[2]), stg + (d * 4 + 2) * 256);
        GLDS16(GADDR(iq[3]), stg + (d * 4 + 3) * 256);
    }
    u32x4 idn = *(const u32x4*)&idsrow[12];

    const int M    = T >> 2;   // full 4-step iterations
    const int tail = T & 3;

    int so = 0;                // slot offset = base % 12 (cycles 0,4,8)
    for (int k = 0; k < M; ++k) {
        const int base = k << 2;
        // 8 newer glds may remain outstanding => slots so..so+3 have landed
        asm volatile("s_waitcnt vmcnt(8)" ::: "memory");
        f32x4 e0 = ld4(stg + ((so + 0) << 8) + l4);
        f32x4 e1 = ld4(stg + ((so + 1) << 8) + l4);
        f32x4 e2 = ld4(stg + ((so + 2) << 8) + l4);
        f32x4 e3 = ld4(stg + ((so + 3) << 8) + l4);
        u32x4 idc = idn;                            // ids for steps base+12..15
        idn = *(const u32x4*)&idsrow[base + 16];    // for next iteration

        // ---- h-independent e-side MFMAs for all 4 steps (fill work) ----
        f16x4 eh0 = pk_f16(e0);
        f16x4 eh1 = pk_f16(e1);
        f16x4 eh2 = pk_f16(e2);
        f16x4 eh3 = pk_f16(e3);
        f16x8 Be0 = __builtin_shufflevector(eh0, eh0, 0, 1, 2, 3, 0, 1, 2, 3);
        f16x8 Be1 = __builtin_shufflevector(eh1, eh1, 0, 1, 2, 3, 0, 1, 2, 3);
        f16x8 Be2 = __builtin_shufflevector(eh2, eh2, 0, 1, 2, 3, 0, 1, 2, 3);
        f16x8 Be3 = __builtin_shufflevector(eh3, eh3, 0, 1, 2, 3, 0, 1, 2, 3);
        f32x4 xr0 = MFMA32(Air, Be0, br4),  xz0 = MFMA32(Aiz, Be0, bz4),  xn0 = MFMA32(Ain, Be0, bxn4);
        f32x4 xr1 = MFMA32(Air, Be1, br4),  xz1 = MFMA32(Aiz, Be1, bz4),  xn1 = MFMA32(Ain, Be1, bxn4);
        f32x4 xr2 = MFMA32(Air, Be2, br4),  xz2 = MFMA32(Aiz, Be2, bz4),  xn2 = MFMA32(Ain, Be2, bxn4);
        f32x4 xr3 = MFMA32(Air, Be3, br4),  xz3 = MFMA32(Aiz, Be3, bz4),  xn3 = MFMA32(Ain, Be3, bxn4);

        // ---- dependent recurrence: ONE MFMA per gate per step ----
        gru_step_h(xr0, xz0, xn0, Ahr, Ahz, Ahn, bhn4, h, hsum, hh);
        gru_step_h(xr1, xz1, xn1, Ahr, Ahz, Ahn, bhn4, h, hsum, hh);
        gru_step_h(xr2, xz2, xn2, Ahr, Ahz, Ahn, bhn4, h, hsum, hh);
        gru_step_h(xr3, xz3, xn3, Ahr, Ahz, Ahn, bhn4, h, hsum, hh);

        // DS reads above long retired (free) — clears WAR for re-staging
        asm volatile("s_waitcnt lgkmcnt(0)" ::: "memory");
        GLDS16(GADDR(idc[0]), stg + ((so + 0) << 8));   // step base+12
        GLDS16(GADDR(idc[1]), stg + ((so + 1) << 8));   // step base+13
        GLDS16(GADDR(idc[2]), stg + ((so + 2) << 8));   // step base+14
        GLDS16(GADDR(idc[3]), stg + ((so + 3) << 8));   // step base+15
        so += 4; if (so == 12) so = 0;
    }
    if (tail) {
        asm volatile("s_waitcnt vmcnt(0)" ::: "memory");
        for (int t = M << 2; t < T; ++t) {
            int sl12 = t % 12;
            f32x4 e = ld4(stg + (sl12 << 8) + l4);
            f16x4 eh = pk_f16(e);
            f16x8 Be = __builtin_shufflevector(eh, eh, 0, 1, 2, 3, 0, 1, 2, 3);
            f32x4 xr = MFMA32(Air, Be, br4);
            f32x4 xz = MFMA32(Aiz, Be, bz4);
            f32x4 xn = MFMA32(Ain, Be, bxn4);
            gru_step_h(xr, xz, xn, Ahr, Ahz, Ahn, bhn4, h, hsum, hh);
        }
    }

    // ---- epilogue: degenerate MHA -> A[b], all_enc row, BN1 stats ----
    const float* itr = item_table + (size_t)ti * 12;
    f32x4 tv0 = ld4(itr), tv1 = ld4(itr + 4), tv2 = ld4(itr + 8);
    f32x4 tv3 = ld4(cat_table + tc * 4);

    f32x4 vq;
#pragma unroll
    for (int q = 0; q < 4; ++q) {
        int row = 32 + 4 * hi + q;
        const float* wv = mha_Win + row * 16;
        vq[q] = mha_bin[row] + dot4(ld4(wv), tv0) + dot4(ld4(wv + 4), tv1)
              + dot4(ld4(wv + 8), tv2) + dot4(ld4(wv + 12), tv3);
    }
    f32x4 vg0, vg1, vg2, vg3;
#pragma unroll
    for (int q = 0; q < 4; ++q) {
        vg0[q] = __shfl_xor(vq[q], (hi ^ 0) << 4);
        vg1[q] = __shfl_xor(vq[q], (hi ^ 1) << 4);
        vg2[q] = __shfl_xor(vq[q], (hi ^ 2) << 4);
        vg3[q] = __shfl_xor(vq[q], (hi ^ 3) << 4);
    }
    f32x4 aj;
#pragma unroll
    for (int q = 0; q < 4; ++q) {
        int row = 4 * hi + q;
        const float* wo = mha_Wout + row * 16;
        aj[q] = mha_bout[row] + dot4(ld4(wo), vg0) + dot4(ld4(wo + 4), vg1)
              + dot4(ld4(wo + 8), vg2) + dot4(ld4(wo + 12), vg3);
    }
    f32x4 avg = aj * hsum;

    f32x4 u4  = ld4(user_table + (size_t)uid * 16 + 4 * hi);
    f32x4 t4v = (hi == 0) ? tv0 : (hi == 1) ? tv1 : (hi == 2) ? tv2 : tv3;

    if (act) {
        float* er = all_enc + b * 48 + 4 * hi;
        *(f32x4*)er        = avg;
        *(f32x4*)(er + 16) = t4v;
        *(f32x4*)(er + 32) = u4;
    }

    const f32x4 zero4 = {0.f, 0.f, 0.f, 0.f};
    f32x4 sa = act ? avg : zero4, st = act ? t4v : zero4, su = act ? u4 : zero4;
    f32x4 qa = sa * sa, qt = st * st, qu = su * su;
#pragma unroll
    for (int m = 1; m <= 8; m <<= 1) {
#pragma unroll
        for (int q = 0; q < 4; ++q) {
            sa[q] += __shfl_xor(sa[q], m);
            st[q] += __shfl_xor(st[q], m);
            su[q] += __shfl_xor(su[q], m);
            qa[q] += __shfl_xor(qa[q], m);
            qt[q] += __shfl_xor(qt[q], m);
            qu[q] += __shfl_xor(qu[q], m);
        }
    }
    if (s == 0) {
        int c = 4 * hi;
#pragma unroll
        for (int q = 0; q < 4; ++q) {
            lds_part[wid][c + q]      = sa[q];
            lds_part[wid][16 + c + q] = st[q];
            lds_part[wid][32 + c + q] = su[q];
            lds_part[wid][48 + c + q] = qa[q];
            lds_part[wid][64 + c + q] = qt[q];
            lds_part[wid][80 + c + q] = qu[q];
        }
    }
    __syncthreads();
    if (tid < 96) {
        float v = lds_part[0][tid] + lds_part[1][tid] + lds_part[2][tid] + lds_part[3][tid];
        atomicAdd(&stats1[tid], v);
    }
}

// ---------------------------------------------------------------------------
// K3: fc1 with BN1-fold computed inline per block (512 blocks).
// ---------------------------------------------------------------------------
__global__ __launch_bounds__(256) void k_fc1(
    const float* __restrict__ all_enc, const float* __restrict__ stats,
    fp fc1_W, fp fc1_b, fp g1, fp b1,
    float* __restrict__ hbuf, float* __restrict__ stats2, int B)
{
    const int tid = threadIdx.x, lane = tid & 63, wid = tid >> 6;
    const int j = lane & 15, sl = lane >> 4;
    __shared__ float kk[48], mm[48];
    __shared__ float part[4][32];

    if (tid < 48) {
        float mu  = stats[tid] / (float)B;
        float var = stats[48 + tid] / (float)B - mu * mu;
        float k   = rsqrtf(var + BN_EPS);
        float gk  = g1[tid] * k;
        kk[tid] = gk;
        mm[tid] = b1[tid] - mu * gk;
    }
    __syncthreads();

    float w[48];
    float bj = fc1_b[j];
#pragma unroll
    for (int q = 0; q < 12; ++q) {
        float4 v = *(const float4*)&fc1_W[j * 48 + q * 4];
        w[q * 4 + 0] = v.x * kk[q * 4 + 0];
        w[q * 4 + 1] = v.y * kk[q * 4 + 1];
        w[q * 4 + 2] = v.z * kk[q * 4 + 2];
        w[q * 4 + 3] = v.w * kk[q * 4 + 3];
        bj += v.x * mm[q * 4 + 0] + v.y * mm[q * 4 + 1]
            + v.z * mm[q * 4 + 2] + v.w * mm[q * 4 + 3];
    }

    float sh = 0.f, sq = 0.f;
    for (long b = (long)blockIdx.x * 16 + wid * 4 + sl; b < B; b += (long)gridDim.x * 16) {
        const float* x = all_enc + b * 48;
        float acc = bj;
#pragma unroll
        for (int q = 0; q < 12; ++q) {
            float4 v = *(const float4*)&x[q * 4];
            acc += w[q * 4] * v.x + w[q * 4 + 1] * v.y + w[q * 4 + 2] * v.z + w[q * 4 + 3] * v.w;
        }
        float h = fmaxf(acc, 0.f);
        hbuf[b * 16 + j] = h;
        sh += h; sq += h * h;
    }
    sh += __shfl_xor(sh, 16); sh += __shfl_xor(sh, 32);
    sq += __shfl_xor(sq, 16); sq += __shfl_xor(sq, 32);
    if (sl == 0) { part[wid][j] = sh; part[wid][16 + j] = sq; }
    __syncthreads();
    if (tid < 32) {
        float v = part[0][tid] + part[1][tid] + part[2][tid] + part[3][tid];
        atomicAdd(&stats2[tid], v);
    }
}

// ---------------------------------------------------------------------------
// K4: logits + softmax, BN2-fold computed inline per block.
// ---------------------------------------------------------------------------
__global__ __launch_bounds__(256) void k_out(
    const float* __restrict__ hbuf, const float* __restrict__ stats2,
    fp fc2_W, fp fc2_b, fp g2, fp b2, float* __restrict__ out, int B)
{
    __shared__ float w[34];
    const int tid = threadIdx.x;
    if (tid < 32) {
        int c = tid & 15;
        float mu  = stats2[c] / (float)B;
        float var = stats2[16 + c] / (float)B - mu * mu;
        float gk  = g2[c] * rsqrtf(var + BN_EPS);
        w[tid] = fc2_W[tid] * gk;
    }
    if (tid < 2) {
        float acc = fc2_b[tid];
        for (int c = 0; c < 16; ++c) {
            float mu  = stats2[c] / (float)B;
            float var = stats2[16 + c] / (float)B - mu * mu;
            float gk  = g2[c] * rsqrtf(var + BN_EPS);
            acc += fc2_W[tid * 16 + c] * (b2[c] - mu * gk);
        }
        w[32 + tid] = acc;
    }
    __syncthreads();
    for (long b = (long)blockIdx.x * blockDim.x + threadIdx.x; b < B;
         b += (long)gridDim.x * blockDim.x) {
        const float* h = hbuf + b * 16;
        float l0 = w[32], l1 = w[33];
#pragma unroll
        for (int q = 0; q < 4; ++q) {
            float4 v = *(const float4*)&h[q * 4];
            l0 += w[q * 4] * v.x + w[q * 4 + 1] * v.y + w[q * 4 + 2] * v.z + w[q * 4 + 3] * v.w;
            l1 += w[16 + q * 4] * v.x + w[17 + q * 4] * v.y + w[18 + q * 4] * v.z + w[19 + q * 4] * v.w;
        }
        float m  = fmaxf(l0, l1);
        float e0 = __expf(l0 - m), e1 = __expf(l1 - m);
        float inv = frcp(e0 + e1);
        float2 p; p.x = e0 * inv; p.y = e1 * inv;
        *(float2*)&out[b * 2] = p;
    }
}

// ---------------------------------------------------------------------------
extern "C" void kernel_launch(void* const* d_in, const int* in_sizes, int n_in,
                              void* d_out, int out_size, void* d_ws, size_t ws_size,
                              hipStream_t stream)
{
    const int* user_id   = (const int*)d_in[0];
    const int* hist_item = (const int*)d_in[1];
    const int* hist_cat  = (const int*)d_in[2];
    const int* tgt_item  = (const int*)d_in[3];
    const int* tgt_cat   = (const int*)d_in[4];
    fp user_table = (fp)d_in[5];
    fp item_table = (fp)d_in[6];
    fp cat_table  = (fp)d_in[7];
    fp Wih = (fp)d_in[8],  Whh = (fp)d_in[9];
    fp bih = (fp)d_in[10], bhh = (fp)d_in[11];
    fp Win = (fp)d_in[12], binp = (fp)d_in[13];
    fp Wout = (fp)d_in[14], bout = (fp)d_in[15];
    fp g1 = (fp)d_in[16], b1 = (fp)d_in[17];
    fp fc1W = (fp)d_in[18], fc1b = (fp)d_in[19];
    fp g2 = (fp)d_in[20], b2 = (fp)d_in[21];
    fp fc2W = (fp)d_in[22], fc2b = (fp)d_in[23];

    const int B = in_sizes[0];
    const int T = in_sizes[1] / B;

    float* ws       = (float*)d_ws;
    float* stats1   = ws;                       // 96
    float* stats2   = ws + 96;                  // 32
    float* all_enc  = ws + 128;                 // B*48 (16B aligned)
    float* hbuf     = all_enc + (size_t)B * 48; // B*16

    hipLaunchKernelGGL(k_zero, dim3(1), dim3(128), 0, stream, ws);

    hipLaunchKernelGGL(k_gru, dim3((B + 63) / 64), dim3(256), 0, stream,
                       user_id, hist_item, hist_cat, tgt_item, tgt_cat,
                       user_table, item_table, cat_table, Whh, bhh, Wih, bih,
                       Win, binp, Wout, bout, all_enc, stats1, B, T);

    hipLaunchKernelGGL(k_fc1, dim3(512), dim3(256), 0, stream,
                       all_enc, stats1, fc1W, fc1b, g1, b1, hbuf, stats2, B);

    hipLaunchKernelGGL(k_out, dim3((B + 255) / 256), dim3(256), 0, stream,
                       hbuf, stats2, fc2W, fc2b, g2, b2, (float*)d_out, B);
}

// Round 17
// 61.298 us; speedup vs baseline: 1.0177x; 1.0177x over previous
//
#include <hip/hip_runtime.h>

#define BN_EPS 1e-5f
#define LOG2E 1.44269504088896340736f

typedef const float* fp;
typedef float f32x4 __attribute__((ext_vector_type(4)));
typedef _Float16 f16x2 __attribute__((ext_vector_type(2)));
typedef _Float16 f16x4 __attribute__((ext_vector_type(4)));
typedef _Float16 f16x8 __attribute__((ext_vector_type(8)));
typedef unsigned u32x4 __attribute__((ext_vector_type(4)));

__device__ __forceinline__ float frcp(float x) { return __builtin_amdgcn_rcpf(x); }
__device__ __forceinline__ float fexp2(float x) { return __builtin_amdgcn_exp2f(x); }
// reference-formula transcendentals (used in k_out, unchanged)
__device__ __forceinline__ float sigm(float x) { return frcp(1.0f + __expf(-x)); }

__device__ __forceinline__ f32x4 ld4(const float* p) { return *(const f32x4*)p; }
__device__ __forceinline__ float dot4(f32x4 a, f32x4 b) {
    return a[0] * b[0] + a[1] * b[1] + a[2] * b[2] + a[3] * b[3];
}

#define MFMA32(A, B, C) __builtin_amdgcn_mfma_f32_16x16x32_f16((A), (B), (C), 0, 0, 0)

// async global->LDS, 16B per lane; dest = uniform base + lane*16 (HW rule).
#define GLDS16(gp, lp) __builtin_amdgcn_global_load_lds( \
    (const __attribute__((address_space(1))) void*)(gp), \
    (__attribute__((address_space(3))) void*)(lp), 16, 0, 0)

// pack f32x4 -> f16x4 via v_cvt_pkrtz (2 inst).
__device__ __forceinline__ f16x4 pk_f16(f32x4 v) {
    f16x2 lo = __builtin_bit_cast(f16x2, __builtin_amdgcn_cvt_pkrtz(v[0], v[1]));
    f16x2 hi = __builtin_bit_cast(f16x2, __builtin_amdgcn_cvt_pkrtz(v[2], v[3]));
    return __builtin_shufflevector(lo, hi, 0, 1, 2, 3);
}

// ---------------------------------------------------------------------------
// K0: zero stats1[96] + stats2[32].
// ---------------------------------------------------------------------------
__global__ void k_zero(float* __restrict__ stats) { stats[threadIdx.x] = 0.f; }

// ---------------------------------------------------------------------------
// K2: MFMA GRU, 16 samples/wave, 4-step unrolled 8-slot ring (best measured
// composition, R15 = 61.46us). Per 4 steps: ONE vmcnt(4) + ONE lgkmcnt(0)
// fence, ids via one ds_read_b128, prefetch distance 7 steps. e/h gate
// split: h-independent e-side MFMAs hoisted per 4-step block; dependent part
// is ONE MFMA per gate. exp-scale constants folded into weights (r,z sets *
// -log2e; n set * +2log2e) so MFMA outputs feed v_exp2 directly; shared rcp
// for r,z. Ceiling note: T=50 serial steps, 2048 waves = 2/SIMD (pinned by
// MFMA N=16 sample mapping); per-step dependent MFMA->trans->VALU chain
// ~130cy latency that 2 waves only partially hide — all pipes <35% busy.
// In-wave ILP (R4/R11), deeper prefetch (R16), grid-barrier fusion (R9) all
// regressed/null. absmax 0.00390625. Requires T <= 52.
// ---------------------------------------------------------------------------
__device__ __forceinline__ void gru_step_h(
    f32x4 xr, f32x4 xz, f32x4 xn,
    const f16x8& Ahr, const f16x8& Ahz, const f16x8& Ahn, const f32x4& bhn4,
    f32x4& h, f32x4& hsum, f16x4& hh)
{
    f16x8 Bh2 = __builtin_shufflevector(hh, hh, 0, 1, 2, 3, 0, 1, 2, 3);
    f32x4 sR = MFMA32(Ahr, Bh2, xr);    // = -1.4427 * (r preact)
    f32x4 sZ = MFMA32(Ahz, Bh2, xz);    // = -1.4427 * (z preact)
    f32x4 hn = MFMA32(Ahn, Bh2, bhn4);  // =  2.8854 * (hn part)
    f32x4 r, z, nv;
#pragma unroll
    for (int q = 0; q < 4; ++q) {
        float a  = fexp2(sR[q]);
        float bb = fexp2(sZ[q]);
        float pa = 1.0f + a, pb = 1.0f + bb;
        float iD = frcp(pa * pb);
        r[q] = pb * iD;
        z[q] = pa * iD;
    }
    f32x4 pre = r * hn + xn;            // = 2.8854 * (n preact)
#pragma unroll
    for (int q = 0; q < 4; ++q)
        nv[q] = 1.0f - 2.0f * frcp(1.0f + fexp2(pre[q]));
    h = z * (h - nv) + nv;
    hsum += h;
    hh = pk_f16(h);
}

__global__ __launch_bounds__(256, 2) void k_gru(
    const int* __restrict__ user_id, const int* __restrict__ hist_item,
    const int* __restrict__ hist_cat, const int* __restrict__ tgt_item,
    const int* __restrict__ tgt_cat,
    fp user_table, fp item_table, fp cat_table,
    fp Whh, fp bhh, fp Wih, fp bih,
    fp mha_Win, fp mha_bin, fp mha_Wout, fp mha_bout,
    float* __restrict__ all_enc, float* __restrict__ stats1, int B, int T)
{
    __shared__ float    s_stage[4][8][256];   // 32KB [wave][slot][lane*4]
    __shared__ unsigned s_ids[4][16 * 68];    // 17.4KB packed (cd<<16)|id
    __shared__ float    lds_part[4][96];

    const int tid  = threadIdx.x;
    const int lane = tid & 63;
    const int wid  = tid >> 6;
    const int s    = lane & 15;
    const int hi   = lane >> 4;

    long b = (long)blockIdx.x * 64 + wid * 16 + s;
    const bool act = (b < B);
    if (!act) b = B - 1;

    // epilogue indices: materialize before the barrier (VMEM retires there)
    const int ti  = tgt_item[b];
    const int tc  = tgt_cat[b];
    const int uid = user_id[b];
    asm volatile("" :: "v"(ti), "v"(tc), "v"(uid));

    const int T1 = T - 1;

    // one-time packed id preload into LDS, padded with clamped ids to idx 63
    {
        const int* ip = hist_item + b * T;
        const int* cp = hist_cat  + b * T;
        unsigned* d = &s_ids[wid][s * 68];
        for (int k = hi; k < 64; k += 4) {
            int src = (k <= T1) ? k : T1;
            d[k] = (unsigned)ip[src] | ((unsigned)cp[src] << 16);
        }
    }

    // ---- weight fragments + constant gate biases (one-time) ----
    // exp-scales folded: r,z sets * -log2(e); n set * +2*log2(e).
    const float sRZ = -LOG2E, sN = 2.0f * LOG2E;
    f32x4 wirf = ld4(&Wih[(0  + s) * 16 + 4 * hi]) * sRZ;
    f32x4 wizf = ld4(&Wih[(16 + s) * 16 + 4 * hi]) * sRZ;
    f32x4 winf = ld4(&Wih[(32 + s) * 16 + 4 * hi]) * sN;
    f32x4 whrf = ld4(&Whh[(0  + s) * 16 + 4 * hi]) * sRZ;
    f32x4 whzf = ld4(&Whh[(16 + s) * 16 + 4 * hi]) * sRZ;
    f32x4 whnf = ld4(&Whh[(32 + s) * 16 + 4 * hi]) * sN;
    f16x4 wir_h = __builtin_convertvector(wirf, f16x4);
    f16x4 wiz_h = __builtin_convertvector(wizf, f16x4);
    f16x4 win_h = __builtin_convertvector(winf, f16x4);
    f16x4 whr_h = __builtin_convertvector(whrf, f16x4);
    f16x4 whz_h = __builtin_convertvector(whzf, f16x4);
    f16x4 whn_h = __builtin_convertvector(whnf, f16x4);
    f16x4 wir_l = __builtin_convertvector(wirf - __builtin_convertvector(wir_h, f32x4), f16x4);
    f16x4 wiz_l = __builtin_convertvector(wizf - __builtin_convertvector(wiz_h, f32x4), f16x4);
    f16x4 win_l = __builtin_convertvector(winf - __builtin_convertvector(win_h, f32x4), f16x4);
    f16x4 whr_l = __builtin_convertvector(whrf - __builtin_convertvector(whr_h, f32x4), f16x4);
    f16x4 whz_l = __builtin_convertvector(whzf - __builtin_convertvector(whz_h, f32x4), f16x4);
    f16x4 whn_l = __builtin_convertvector(whnf - __builtin_convertvector(whn_h, f32x4), f16x4);
    f16x8 Air = __builtin_shufflevector(wir_h, wir_l, 0, 1, 2, 3, 4, 5, 6, 7);
    f16x8 Aiz = __builtin_shufflevector(wiz_h, wiz_l, 0, 1, 2, 3, 4, 5, 6, 7);
    f16x8 Ain = __builtin_shufflevector(win_h, win_l, 0, 1, 2, 3, 4, 5, 6, 7);
    f16x8 Ahr = __builtin_shufflevector(whr_h, whr_l, 0, 1, 2, 3, 4, 5, 6, 7);
    f16x8 Ahz = __builtin_shufflevector(whz_h, whz_l, 0, 1, 2, 3, 4, 5, 6, 7);
    f16x8 Ahn = __builtin_shufflevector(whn_h, whn_l, 0, 1, 2, 3, 4, 5, 6, 7);
    const f32x4 br4  = (ld4(&bih[4 * hi])      + ld4(&bhh[4 * hi]))      * sRZ;
    const f32x4 bz4  = (ld4(&bih[16 + 4 * hi]) + ld4(&bhh[16 + 4 * hi])) * sRZ;
    const f32x4 bxn4 = ld4(&bih[32 + 4 * hi]) * sN;
    const f32x4 bhn4 = ld4(&bhh[32 + 4 * hi]) * sN;

    f32x4 h = {0.f, 0.f, 0.f, 0.f}, hsum = {0.f, 0.f, 0.f, 0.f};
    f16x4 hh = {};

    __syncthreads();   // ids ready; all prologue VMEM drained here

    const unsigned* idsrow = &s_ids[wid][s * 68];
    float* stg = &s_stage[wid][0][0];
    const int l4 = lane * 4;

    // per-lane gather parameters
    const char*   gb   = (hi < 3) ? (const char*)item_table + hi * 16
                                  : (const char*)cat_table;
    const unsigned gsh  = (hi < 3) ? 0u : 16u;
    const unsigned gmul = (hi < 3) ? 48u : 16u;
#define GADDR(pk) (gb + (size_t)(((pk) >> gsh) & 0xffffu) * gmul)

    // prologue: stage slots 0..7 (steps 0..7, clamped); prefetch ids[8..11]
    {
        u32x4 i03 = *(const u32x4*)&idsrow[0];
        u32x4 i47 = *(const u32x4*)&idsrow[4];
        GLDS16(GADDR(i03[0]), stg);
        GLDS16(GADDR(i03[1]), stg + 256);
        GLDS16(GADDR(i03[2]), stg + 512);
        GLDS16(GADDR(i03[3]), stg + 768);
        GLDS16(GADDR(i47[0]), stg + 1024);
        GLDS16(GADDR(i47[1]), stg + 1280);
        GLDS16(GADDR(i47[2]), stg + 1536);
        GLDS16(GADDR(i47[3]), stg + 1792);
    }
    u32x4 idn = *(const u32x4*)&idsrow[8];

    const int M    = T >> 2;   // full 4-step iterations
    const int tail = T & 3;

    for (int k = 0; k < M; ++k) {
        const int base = k << 2;
        asm volatile("s_waitcnt vmcnt(4)" ::: "memory");
        f32x4 e0 = ld4(stg + (((base + 0) & 7) << 8) + l4);
        f32x4 e1 = ld4(stg + (((base + 1) & 7) << 8) + l4);
        f32x4 e2 = ld4(stg + (((base + 2) & 7) << 8) + l4);
        f32x4 e3 = ld4(stg + (((base + 3) & 7) << 8) + l4);
        u32x4 idc = idn;
        idn = *(const u32x4*)&idsrow[base + 12];

        // ---- h-independent e-side MFMAs for all 4 steps (fill work) ----
        f16x4 eh0 = pk_f16(e0);
        f16x4 eh1 = pk_f16(e1);
        f16x4 eh2 = pk_f16(e2);
        f16x4 eh3 = pk_f16(e3);
        f16x8 Be0 = __builtin_shufflevector(eh0, eh0, 0, 1, 2, 3, 0, 1, 2, 3);
        f16x8 Be1 = __builtin_shufflevector(eh1, eh1, 0, 1, 2, 3, 0, 1, 2, 3);
        f16x8 Be2 = __builtin_shufflevector(eh2, eh2, 0, 1, 2, 3, 0, 1, 2, 3);
        f16x8 Be3 = __builtin_shufflevector(eh3, eh3, 0, 1, 2, 3, 0, 1, 2, 3);
        f32x4 xr0 = MFMA32(Air, Be0, br4),  xz0 = MFMA32(Aiz, Be0, bz4),  xn0 = MFMA32(Ain, Be0, bxn4);
        f32x4 xr1 = MFMA32(Air, Be1, br4),  xz1 = MFMA32(Aiz, Be1, bz4),  xn1 = MFMA32(Ain, Be1, bxn4);
        f32x4 xr2 = MFMA32(Air, Be2, br4),  xz2 = MFMA32(Aiz, Be2, bz4),  xn2 = MFMA32(Ain, Be2, bxn4);
        f32x4 xr3 = MFMA32(Air, Be3, br4),  xz3 = MFMA32(Aiz, Be3, bz4),  xn3 = MFMA32(Ain, Be3, bxn4);

        // ---- dependent recurrence: ONE MFMA per gate per step ----
        gru_step_h(xr0, xz0, xn0, Ahr, Ahz, Ahn, bhn4, h, hsum, hh);
        gru_step_h(xr1, xz1, xn1, Ahr, Ahz, Ahn, bhn4, h, hsum, hh);
        gru_step_h(xr2, xz2, xn2, Ahr, Ahz, Ahn, bhn4, h, hsum, hh);
        gru_step_h(xr3, xz3, xn3, Ahr, Ahz, Ahn, bhn4, h, hsum, hh);

        asm volatile("s_waitcnt lgkmcnt(0)" ::: "memory");
        GLDS16(GADDR(idc[0]), stg + (((base + 0) & 7) << 8));
        GLDS16(GADDR(idc[1]), stg + (((base + 1) & 7) << 8));
        GLDS16(GADDR(idc[2]), stg + (((base + 2) & 7) << 8));
        GLDS16(GADDR(idc[3]), stg + (((base + 3) & 7) << 8));
    }
    if (tail) {
        asm volatile("s_waitcnt vmcnt(0)" ::: "memory");
        for (int t = M << 2; t < T; ++t) {
            f32x4 e = ld4(stg + ((t & 7) << 8) + l4);
            f16x4 eh = pk_f16(e);
            f16x8 Be = __builtin_shufflevector(eh, eh, 0, 1, 2, 3, 0, 1, 2, 3);
            f32x4 xr = MFMA32(Air, Be, br4);
            f32x4 xz = MFMA32(Aiz, Be, bz4);
            f32x4 xn = MFMA32(Ain, Be, bxn4);
            gru_step_h(xr, xz, xn, Ahr, Ahz, Ahn, bhn4, h, hsum, hh);
        }
    }

    // ---- epilogue: degenerate MHA -> A[b], all_enc row, BN1 stats ----
    const float* itr = item_table + (size_t)ti * 12;
    f32x4 tv0 = ld4(itr), tv1 = ld4(itr + 4), tv2 = ld4(itr + 8);
    f32x4 tv3 = ld4(cat_table + tc * 4);

    f32x4 vq;
#pragma unroll
    for (int q = 0; q < 4; ++q) {
        int row = 32 + 4 * hi + q;
        const float* wv = mha_Win + row * 16;
        vq[q] = mha_bin[row] + dot4(ld4(wv), tv0) + dot4(ld4(wv + 4), tv1)
              + dot4(ld4(wv + 8), tv2) + dot4(ld4(wv + 12), tv3);
    }
    f32x4 vg0, vg1, vg2, vg3;
#pragma unroll
    for (int q = 0; q < 4; ++q) {
        vg0[q] = __shfl_xor(vq[q], (hi ^ 0) << 4);
        vg1[q] = __shfl_xor(vq[q], (hi ^ 1) << 4);
        vg2[q] = __shfl_xor(vq[q], (hi ^ 2) << 4);
        vg3[q] = __shfl_xor(vq[q], (hi ^ 3) << 4);
    }
    f32x4 aj;
#pragma unroll
    for (int q = 0; q < 4; ++q) {
        int row = 4 * hi + q;
        const float* wo = mha_Wout + row * 16;
        aj[q] = mha_bout[row] + dot4(ld4(wo), vg0) + dot4(ld4(wo + 4), vg1)
              + dot4(ld4(wo + 8), vg2) + dot4(ld4(wo + 12), vg3);
    }
    f32x4 avg = aj * hsum;

    f32x4 u4  = ld4(user_table + (size_t)uid * 16 + 4 * hi);
    f32x4 t4v = (hi == 0) ? tv0 : (hi == 1) ? tv1 : (hi == 2) ? tv2 : tv3;

    if (act) {
        float* er = all_enc + b * 48 + 4 * hi;
        *(f32x4*)er        = avg;
        *(f32x4*)(er + 16) = t4v;
        *(f32x4*)(er + 32) = u4;
    }

    const f32x4 zero4 = {0.f, 0.f, 0.f, 0.f};
    f32x4 sa = act ? avg : zero4, st = act ? t4v : zero4, su = act ? u4 : zero4;
    f32x4 qa = sa * sa, qt = st * st, qu = su * su;
#pragma unroll
    for (int m = 1; m <= 8; m <<= 1) {
#pragma unroll
        for (int q = 0; q < 4; ++q) {
            sa[q] += __shfl_xor(sa[q], m);
            st[q] += __shfl_xor(st[q], m);
            su[q] += __shfl_xor(su[q], m);
            qa[q] += __shfl_xor(qa[q], m);
            qt[q] += __shfl_xor(qt[q], m);
            qu[q] += __shfl_xor(qu[q], m);
        }
    }
    if (s == 0) {
        int c = 4 * hi;
#pragma unroll
        for (int q = 0; q < 4; ++q) {
            lds_part[wid][c + q]      = sa[q];
            lds_part[wid][16 + c + q] = st[q];
            lds_part[wid][32 + c + q] = su[q];
            lds_part[wid][48 + c + q] = qa[q];
            lds_part[wid][64 + c + q] = qt[q];
            lds_part[wid][80 + c + q] = qu[q];
        }
    }
    __syncthreads();
    if (tid < 96) {
        float v = lds_part[0][tid] + lds_part[1][tid] + lds_part[2][tid] + lds_part[3][tid];
        atomicAdd(&stats1[tid], v);
    }
}

// ---------------------------------------------------------------------------
// K3: fc1 with BN1-fold computed inline per block (512 blocks).
// ---------------------------------------------------------------------------
__global__ __launch_bounds__(256) void k_fc1(
    const float* __restrict__ all_enc, const float* __restrict__ stats,
    fp fc1_W, fp fc1_b, fp g1, fp b1,
    float* __restrict__ hbuf, float* __restrict__ stats2, int B)
{
    const int tid = threadIdx.x, lane = tid & 63, wid = tid >> 6;
    const int j = lane & 15, sl = lane >> 4;
    __shared__ float kk[48], mm[48];
    __shared__ float part[4][32];

    if (tid < 48) {
        float mu  = stats[tid] / (float)B;
        float var = stats[48 + tid] / (float)B - mu * mu;
        float k   = rsqrtf(var + BN_EPS);
        float gk  = g1[tid] * k;
        kk[tid] = gk;
        mm[tid] = b1[tid] - mu * gk;
    }
    __syncthreads();

    float w[48];
    float bj = fc1_b[j];
#pragma unroll
    for (int q = 0; q < 12; ++q) {
        float4 v = *(const float4*)&fc1_W[j * 48 + q * 4];
        w[q * 4 + 0] = v.x * kk[q * 4 + 0];
        w[q * 4 + 1] = v.y * kk[q * 4 + 1];
        w[q * 4 + 2] = v.z * kk[q * 4 + 2];
        w[q * 4 + 3] = v.w * kk[q * 4 + 3];
        bj += v.x * mm[q * 4 + 0] + v.y * mm[q * 4 + 1]
            + v.z * mm[q * 4 + 2] + v.w * mm[q * 4 + 3];
    }

    float sh = 0.f, sq = 0.f;
    for (long b = (long)blockIdx.x * 16 + wid * 4 + sl; b < B; b += (long)gridDim.x * 16) {
        const float* x = all_enc + b * 48;
        float acc = bj;
#pragma unroll
        for (int q = 0; q < 12; ++q) {
            float4 v = *(const float4*)&x[q * 4];
            acc += w[q * 4] * v.x + w[q * 4 + 1] * v.y + w[q * 4 + 2] * v.z + w[q * 4 + 3] * v.w;
        }
        float h = fmaxf(acc, 0.f);
        hbuf[b * 16 + j] = h;
        sh += h; sq += h * h;
    }
    sh += __shfl_xor(sh, 16); sh += __shfl_xor(sh, 32);
    sq += __shfl_xor(sq, 16); sq += __shfl_xor(sq, 32);
    if (sl == 0) { part[wid][j] = sh; part[wid][16 + j] = sq; }
    __syncthreads();
    if (tid < 32) {
        float v = part[0][tid] + part[1][tid] + part[2][tid] + part[3][tid];
        atomicAdd(&stats2[tid], v);
    }
}

// ---------------------------------------------------------------------------
// K4: logits + softmax, BN2-fold computed inline per block.
// ---------------------------------------------------------------------------
__global__ __launch_bounds__(256) void k_out(
    const float* __restrict__ hbuf, const float* __restrict__ stats2,
    fp fc2_W, fp fc2_b, fp g2, fp b2, float* __restrict__ out, int B)
{
    __shared__ float w[34];
    const int tid = threadIdx.x;
    if (tid < 32) {
        int c = tid & 15;
        float mu  = stats2[c] / (float)B;
        float var = stats2[16 + c] / (float)B - mu * mu;
        float gk  = g2[c] * rsqrtf(var + BN_EPS);
        w[tid] = fc2_W[tid] * gk;
    }
    if (tid < 2) {
        float acc = fc2_b[tid];
        for (int c = 0; c < 16; ++c) {
            float mu  = stats2[c] / (float)B;
            float var = stats2[16 + c] / (float)B - mu * mu;
            float gk  = g2[c] * rsqrtf(var + BN_EPS);
            acc += fc2_W[tid * 16 + c] * (b2[c] - mu * gk);
        }
        w[32 + tid] = acc;
    }
    __syncthreads();
    for (long b = (long)blockIdx.x * blockDim.x + threadIdx.x; b < B;
         b += (long)gridDim.x * blockDim.x) {
        const float* h = hbuf + b * 16;
        float l0 = w[32], l1 = w[33];
#pragma unroll
        for (int q = 0; q < 4; ++q) {
            float4 v = *(const float4*)&h[q * 4];
            l0 += w[q * 4] * v.x + w[q * 4 + 1] * v.y + w[q * 4 + 2] * v.z + w[q * 4 + 3] * v.w;
            l1 += w[16 + q * 4] * v.x + w[17 + q * 4] * v.y + w[18 + q * 4] * v.z + w[19 + q * 4] * v.w;
        }
        float m  = fmaxf(l0, l1);
        float e0 = __expf(l0 - m), e1 = __expf(l1 - m);
        float inv = frcp(e0 + e1);
        float2 p; p.x = e0 * inv; p.y = e1 * inv;
        *(float2*)&out[b * 2] = p;
    }
}

// ---------------------------------------------------------------------------
extern "C" void kernel_launch(void* const* d_in, const int* in_sizes, int n_in,
                              void* d_out, int out_size, void* d_ws, size_t ws_size,
                              hipStream_t stream)
{
    const int* user_id   = (const int*)d_in[0];
    const int* hist_item = (const int*)d_in[1];
    const int* hist_cat  = (const int*)d_in[2];
    const int* tgt_item  = (const int*)d_in[3];
    const int* tgt_cat   = (const int*)d_in[4];
    fp user_table = (fp)d_in[5];
    fp item_table = (fp)d_in[6];
    fp cat_table  = (fp)d_in[7];
    fp Wih = (fp)d_in[8],  Whh = (fp)d_in[9];
    fp bih = (fp)d_in[10], bhh = (fp)d_in[11];
    fp Win = (fp)d_in[12], binp = (fp)d_in[13];
    fp Wout = (fp)d_in[14], bout = (fp)d_in[15];
    fp g1 = (fp)d_in[16], b1 = (fp)d_in[17];
    fp fc1W = (fp)d_in[18], fc1b = (fp)d_in[19];
    fp g2 = (fp)d_in[20], b2 = (fp)d_in[21];
    fp fc2W = (fp)d_in[22], fc2b = (fp)d_in[23];

    const int B = in_sizes[0];
    const int T = in_sizes[1] / B;

    float* ws       = (float*)d_ws;
    float* stats1   = ws;                       // 96
    float* stats2   = ws + 96;                  // 32
    float* all_enc  = ws + 128;                 // B*48 (16B aligned)
    float* hbuf     = all_enc + (size_t)B * 48; // B*16

    hipLaunchKernelGGL(k_zero, dim3(1), dim3(128), 0, stream, ws);

    hipLaunchKernelGGL(k_gru, dim3((B + 63) / 64), dim3(256), 0, stream,
                       user_id, hist_item, hist_cat, tgt_item, tgt_cat,
                       user_table, item_table, cat_table, Whh, bhh, Wih, bih,
                       Win, binp, Wout, bout, all_enc, stats1, B, T);

    hipLaunchKernelGGL(k_fc1, dim3(512), dim3(256), 0, stream,
                       all_enc, stats1, fc1W, fc1b, g1, b1, hbuf, stats2, B);

    hipLaunchKernelGGL(k_out, dim3((B + 255) / 256), dim3(256), 0, stream,
                       hbuf, stats2, fc2W, fc2b, g2, b2, (float*)d_out, B);
}